// Round 5
// baseline (148.497 us; speedup 1.0000x reference)
//
#include <hip/hip_runtime.h>

#define NCODES 512
#define DIM 128
#define NROWS (64*2048)          // 131072
#define QN (NROWS*DIM)           // 16777216
#define BLK_ROWS 128
#define NBLOCKS (NROWS/BLK_ROWS) // 1024
#define NWAVES 4
#define HALF 256                 // codes per LDS pass

typedef __attribute__((ext_vector_type(8))) short short8;
typedef __attribute__((ext_vector_type(4))) float f32x4;

__device__ __forceinline__ unsigned short f2bf(float f) {
  unsigned u = __builtin_bit_cast(unsigned, f);
  u += 0x7FFFu + ((u >> 16) & 1u);   // RNE
  return (unsigned short)(u >> 16);
}

#define GLOAD_LDS16(gp, lp) __builtin_amdgcn_global_load_lds( \
    (__attribute__((address_space(1))) void*)(gp), \
    (__attribute__((address_space(3))) void*)(lp), 16, 0, 0)

// ---------------- prep: bf16 codebook + per-code weights ----------------
__global__ void vq_prep(const float* __restrict__ emb, const float* __restrict__ scaling,
                        unsigned short* __restrict__ emb_bf,
                        float* __restrict__ wv, float* __restrict__ wse,
                        float* __restrict__ wrcp) {
  int k = blockIdx.x;
  int l = threadIdx.x; // 64 lanes
  float2 v = ((const float2*)(emb + k * DIM))[l];
  float ss = v.x * v.x + v.y * v.y;
#pragma unroll
  for (int m = 1; m < 64; m <<= 1) ss += __shfl_xor(ss, m);
  unsigned pack = (unsigned)f2bf(v.x) | ((unsigned)f2bf(v.y) << 16);
  ((unsigned*)emb_bf)[k * 64 + l] = pack;
  if (l == 0) {
    float hr = 40.0f + (float)k * (140.0f / 511.0f);
    float wt = 1.0f + scaling[k] * ((hr - 100.0f) * (1.0f / 70.0f));
    wv[k] = wt;
    wse[k] = wt * ss;        // w_k * ||e_k||^2
    wrcp[k] = 1.0f / wt;     // exact IEEE divide
  }
}

// ---------------- main ----------------
// 1024 blocks x 256 threads (4 waves, 32 rows/wave). Codebook swept in two
// 256-code passes through a 64KB fragment-ordered LDS buffer (re-staged from
// L2 between passes) so LDS fits 2 blocks/CU -> co-resident blocks overlap
// HBM read/store phases with LDS/MFMA sweep phases.
struct SmemT {
  unsigned short frag[HALF * DIM]; // 65536 B, fragment-ordered, one half
  float w[NCODES];
  float wse[NCODES];
  float wrcp[NCODES];
  int idx[BLK_ROWS];
};

__global__ __launch_bounds__(256, 2) void vq_main(
    const float* __restrict__ x,
    const float* __restrict__ emb32,
    const unsigned short* __restrict__ emb_bf,
    const float* __restrict__ wv,
    const float* __restrict__ wse,
    const float* __restrict__ wrcp,
    float* __restrict__ out_q,
    float* __restrict__ out_idx,
    float* __restrict__ partials) {
  __shared__ SmemT sm;
  const int tid = threadIdx.x;
  const int wave = tid >> 6, lane = tid & 63;
  const int g = lane >> 4, lr = lane & 15;
  const long rowbase = (long)blockIdx.x * BLK_ROWS + wave * 32;
  const uint4* __restrict__ csrc = (const uint4*)emb_bf;  // row-major 16B slots

  // --- Issue x loads (registers) ---
  float4 xv[2][4][2];
#pragma unroll
  for (int rg = 0; rg < 2; rg++) {
    const float* xr = x + (rowbase + rg * 16 + lr) * DIM + g * 8;
#pragma unroll
    for (int c = 0; c < 4; c++) {
      xv[rg][c][0] = *(const float4*)(xr + c * 32);
      xv[rg][c][1] = *(const float4*)(xr + c * 32 + 4);
    }
  }

  // --- Stage pass-0 codebook half (codes 0..255), fragment-ordered.
  // dest slot d (local to 64KB buf): tl=d>>8, c=(d>>6)&3, gg=(d>>4)&3, rr=d&15
  // holds code tl*16+rr (+pass*256), k-chunk c*32+gg*8.
#pragma unroll
  for (int i = 0; i < 16; i++) {
    int winst = wave * 16 + i;
    int d = winst * 64 + lane;
    int tl = d >> 8, c = (d >> 6) & 3, gg = (d >> 4) & 3, rr = d & 15;
    int s = (tl * 16 + rr) * 16 + c * 4 + gg;        // pass 0: code = tl*16+rr
    GLOAD_LDS16(csrc + s, (char*)sm.frag + winst * 1024);
  }
#pragma unroll
  for (int j = 0; j < 2; j++) {
    int k = tid + j * 256;
    sm.w[k] = wv[k]; sm.wse[k] = wse[k]; sm.wrcp[k] = wrcp[k];
  }

  // --- Convert x to A fragments + row sumsq (VALU; overlaps staging).
  short8 a[2][4];
  float sr[2][4];
  {
    float srow[2];
#pragma unroll
    for (int rg = 0; rg < 2; rg++) {
      float ss = 0.f;
#pragma unroll
      for (int c = 0; c < 4; c++) {
        float4 v0 = xv[rg][c][0];
        float4 v1 = xv[rg][c][1];
        ss += v0.x * v0.x + v0.y * v0.y + v0.z * v0.z + v0.w * v0.w;
        ss += v1.x * v1.x + v1.y * v1.y + v1.z * v1.z + v1.w * v1.w;
        short8 av;
        av[0] = (short)f2bf(v0.x); av[1] = (short)f2bf(v0.y);
        av[2] = (short)f2bf(v0.z); av[3] = (short)f2bf(v0.w);
        av[4] = (short)f2bf(v1.x); av[5] = (short)f2bf(v1.y);
        av[6] = (short)f2bf(v1.z); av[7] = (short)f2bf(v1.w);
        a[rg][c] = av;
      }
      ss += __shfl_xor(ss, 16);
      ss += __shfl_xor(ss, 32);
      srow[rg] = ss;
    }
#pragma unroll
    for (int rg = 0; rg < 2; rg++)
#pragma unroll
      for (int r = 0; r < 4; r++)
        sr[rg][r] = __shfl(srow[rg], g * 4 + r);  // s of C-row 4g+r
  }

  // --- Two codebook passes; running weighted-argmin carries across.
  float vmin[2][4];
  int imin[2][4];
#pragma unroll
  for (int rg = 0; rg < 2; rg++)
#pragma unroll
    for (int r = 0; r < 4; r++) { vmin[rg][r] = 3.0e38f; imin[rg][r] = 0; }

  const short8* __restrict__ bbase = (const short8*)sm.frag + lane;
#pragma unroll
  for (int pass = 0; pass < 2; pass++) {
    if (pass == 1) {
      __syncthreads();  // all waves done reading pass-0 buffer
#pragma unroll
      for (int i = 0; i < 16; i++) {
        int winst = wave * 16 + i;
        int d = winst * 64 + lane;
        int tl = d >> 8, c = (d >> 6) & 3, gg = (d >> 4) & 3, rr = d & 15;
        int s = ((HALF + tl * 16 + rr)) * 16 + c * 4 + gg;  // codes 256..511
        GLOAD_LDS16(csrc + s, (char*)sm.frag + winst * 1024);
      }
    }
    __syncthreads();  // staging complete (barrier drains vmcnt)

    for (int tl = 0; tl < 16; tl++) {
      const int code = pass * HALF + tl * 16 + lr;
      const float wt = sm.w[code];
      const float bb = sm.wse[code];
      const float m2w = -2.0f * wt;
      f32x4 acc0 = {0.f, 0.f, 0.f, 0.f};
      f32x4 acc1 = {0.f, 0.f, 0.f, 0.f};
#pragma unroll
      for (int c = 0; c < 4; c++) {
        short8 bf = bbase[(tl * 4 + c) * 64];
        acc0 = __builtin_amdgcn_mfma_f32_16x16x32_bf16(a[0][c], bf, acc0, 0, 0, 0);
        acc1 = __builtin_amdgcn_mfma_f32_16x16x32_bf16(a[1][c], bf, acc1, 0, 0, 0);
      }
#pragma unroll
      for (int r = 0; r < 4; r++) {
        float v0 = fmaf(m2w, acc0[r], fmaf(wt, sr[0][r], bb));
        float v1 = fmaf(m2w, acc1[r], fmaf(wt, sr[1][r], bb));
        if (v0 < vmin[0][r]) { vmin[0][r] = v0; imin[0][r] = code; }
        if (v1 < vmin[1][r]) { vmin[1][r] = v1; imin[1][r] = code; }
      }
    }
  }

  // --- Butterfly min-reduce across 16 lanes (tie -> smaller index).
#pragma unroll
  for (int m = 1; m <= 8; m <<= 1) {
#pragma unroll
    for (int rg = 0; rg < 2; rg++)
#pragma unroll
      for (int r = 0; r < 4; r++) {
        float ov = __shfl_xor(vmin[rg][r], m);
        int oi = __shfl_xor(imin[rg][r], m);
        if (ov < vmin[rg][r] || (ov == vmin[rg][r] && oi < imin[rg][r])) {
          vmin[rg][r] = ov; imin[rg][r] = oi;
        }
      }
  }

  // --- Winner processing: loss via dist = vmin * (1/w[imin]); idx -> LDS.
  {
    float l0 = 0.f;
#pragma unroll
    for (int rg = 0; rg < 2; rg++)
#pragma unroll
      for (int r = 0; r < 4; r++) {
        int ci = imin[rg][r];
        l0 = fmaf(vmin[rg][r], sm.wrcp[ci], l0);
        if (lr == 0) sm.idx[wave * 32 + rg * 16 + g * 4 + r] = ci;
      }
    // group-wide values identical; two xors add one lane per other group ->
    // exact sum over the wave's 32 rows (no replication factor).
    l0 += __shfl_xor(l0, 16);
    l0 += __shfl_xor(l0, 32);
    if (lane == 0) partials[blockIdx.x * NWAVES + wave] = l0;
  }
  __syncthreads();

  // --- Coalesced output: gather f32 codebook rows, contiguous uint4 stores.
  {
    const uint4* __restrict__ esrc = (const uint4*)emb32;   // 32 uint4 per row
    uint4* __restrict__ outu = (uint4*)(out_q + (long)blockIdx.x * BLK_ROWS * DIM);
#pragma unroll
    for (int i = 0; i < 16; i++) {
      int pos = i * 256 + tid;        // uint4 index within block tile (4096)
      int row = pos >> 5, k = pos & 31;
      int code = sm.idx[row];
      outu[pos] = esrc[code * 32 + k];
    }
    if (tid < BLK_ROWS)
      out_idx[(long)blockIdx.x * BLK_ROWS + tid] = (float)sm.idx[tid];
  }
}

// ---------------- deterministic loss reduction ----------------
__global__ void vq_loss(const float* __restrict__ partials, float* __restrict__ out_loss) {
  __shared__ float red[16];
  const int t = threadIdx.x;
  float s = 0.f;
  for (int i = t; i < NBLOCKS * NWAVES; i += 1024) s += partials[i];
#pragma unroll
  for (int m = 1; m < 64; m <<= 1) s += __shfl_xor(s, m);
  if ((t & 63) == 0) red[t >> 6] = s;
  __syncthreads();
  if (t == 0) {
    float tot = 0.f;
    for (int i = 0; i < 16; i++) tot += red[i];
    // loss = (1 + 0.6) * mean((q - x)^2) over all QN elements
    out_loss[0] = tot * (1.6f / (float)QN);
  }
}

extern "C" void kernel_launch(void* const* d_in, const int* in_sizes, int n_in,
                              void* d_out, int out_size, void* d_ws, size_t ws_size,
                              hipStream_t stream) {
  const float* x = (const float*)d_in[0];
  const float* emb = (const float*)d_in[1];
  const float* scaling = (const float*)d_in[2];

  float* out_q = (float*)d_out;
  float* out_loss = out_q + QN;
  float* out_idx = out_q + QN + 1;

  unsigned short* emb_bf = (unsigned short*)d_ws;
  float* wv = (float*)((char*)d_ws + NCODES * DIM * 2);
  float* wse = wv + NCODES;
  float* wrcp = wse + NCODES;
  float* partials = wrcp + NCODES;

  vq_prep<<<NCODES, 64, 0, stream>>>(emb, scaling, emb_bf, wv, wse, wrcp);
  vq_main<<<NBLOCKS, 256, 0, stream>>>(x, emb, emb_bf, wv, wse, wrcp,
                                       out_q, out_idx, partials);
  vq_loss<<<1, 1024, 0, stream>>>(partials, out_loss);
}

// Round 7
// 50.109 us; speedup vs baseline: 2.9635x; 2.9635x over previous
//
#include <hip/hip_runtime.h>

#define NCODES 512
#define DIM 128
#define NROWS (64*2048)          // 131072
#define QN (NROWS*DIM)           // 16777216
#define BLK_ROWS 512
#define NBLOCKS (NROWS/BLK_ROWS) // 256
#define NWAVES 16                // 1024 threads, 32 rows/wave

typedef __attribute__((ext_vector_type(8))) short short8;
typedef __attribute__((ext_vector_type(4))) float f32x4;

__device__ __forceinline__ unsigned short f2bf(float f) {
  unsigned u = __builtin_bit_cast(unsigned, f);
  u += 0x7FFFu + ((u >> 16) & 1u);   // RNE
  return (unsigned short)(u >> 16);
}

#define GLOAD_LDS16(gp, lp) __builtin_amdgcn_global_load_lds( \
    (__attribute__((address_space(1))) void*)(gp), \
    (__attribute__((address_space(3))) void*)(lp), 16, 0, 0)

// ---------------- prep: bf16 codebook + per-code weights ----------------
__global__ void vq_prep(const float* __restrict__ emb, const float* __restrict__ scaling,
                        unsigned short* __restrict__ emb_bf,
                        float* __restrict__ wv, float* __restrict__ wse,
                        float* __restrict__ wrcp) {
  int k = blockIdx.x;
  int l = threadIdx.x; // 64 lanes
  float2 v = ((const float2*)(emb + k * DIM))[l];
  float ss = v.x * v.x + v.y * v.y;
#pragma unroll
  for (int m = 1; m < 64; m <<= 1) ss += __shfl_xor(ss, m);
  unsigned pack = (unsigned)f2bf(v.x) | ((unsigned)f2bf(v.y) << 16);
  ((unsigned*)emb_bf)[k * 64 + l] = pack;
  if (l == 0) {
    float hr = 40.0f + (float)k * (140.0f / 511.0f);
    float wt = 1.0f + scaling[k] * ((hr - 100.0f) * (1.0f / 70.0f));
    wv[k] = wt;
    wse[k] = wt * ss;        // w_k * ||e_k||^2
    wrcp[k] = 1.0f / wt;     // exact IEEE divide
  }
}

// ---------------- main ----------------
// R4 skeleton: 256 blocks x 1024 threads (16 waves, 32 rows/wave), codebook
// staged ONCE fragment-ordered (conflict-free), ONE barrier. Store phase is
// wave-owned + register-only (codes via compile-time shfl from the butterfly
// result) -> no sm.idx, no second barrier, waves drift so store VMEM overlaps
// other waves' LDS/MFMA sweep. LDS is read-only after the staging barrier.
struct SmemT {
  unsigned short frag[NCODES * DIM]; // 131072 B
  float w[NCODES];
  float wse[NCODES];
  float wrcp[NCODES];
};

__global__ __launch_bounds__(1024, 4) void vq_main(
    const float* __restrict__ x,
    const float* __restrict__ emb32,
    const unsigned short* __restrict__ emb_bf,
    const float* __restrict__ wv,
    const float* __restrict__ wse,
    const float* __restrict__ wrcp,
    float* __restrict__ out_q,
    float* __restrict__ out_idx,
    float* __restrict__ partials) {
  __shared__ SmemT sm;
  const int tid = threadIdx.x;
  const int wave = tid >> 6, lane = tid & 63;
  const int g = lane >> 4, lr = lane & 15;
  const long rowbase = (long)blockIdx.x * BLK_ROWS + wave * 32;

  // --- Issue x loads (registers) ---
  float4 xv[2][4][2];
#pragma unroll
  for (int rg = 0; rg < 2; rg++) {
    const float* xr = x + (rowbase + rg * 16 + lr) * DIM + g * 8;
#pragma unroll
    for (int c = 0; c < 4; c++) {
      xv[rg][c][0] = *(const float4*)(xr + c * 32);
      xv[rg][c][1] = *(const float4*)(xr + c * 32 + 4);
    }
  }

  // --- Issue codebook staging: global_load_lds, frag-order via source swizzle.
  {
    const uint4* src = (const uint4*)emb_bf;
#pragma unroll
    for (int i = 0; i < 8; i++) {
      int winst = wave * 8 + i;
      int d = winst * 64 + lane;                 // dest 16B slot 0..8191
      int t = d >> 8, c = (d >> 6) & 3, gg = (d >> 4) & 3, rr = d & 15;
      int s = (t * 16 + rr) * 16 + c * 4 + gg;   // source slot (row-major)
      GLOAD_LDS16(src + s, (char*)sm.frag + winst * 1024);
    }
    if (tid < NCODES) {
      sm.w[tid] = wv[tid];
      sm.wse[tid] = wse[tid];
      sm.wrcp[tid] = wrcp[tid];
    }
  }

  // --- Convert x to A fragments + row sumsq (overlaps staging latency).
  short8 a[2][4];
  float sr[2][4];
  {
    float srow[2];
#pragma unroll
    for (int rg = 0; rg < 2; rg++) {
      float ss = 0.f;
#pragma unroll
      for (int c = 0; c < 4; c++) {
        float4 v0 = xv[rg][c][0];
        float4 v1 = xv[rg][c][1];
        ss += v0.x * v0.x + v0.y * v0.y + v0.z * v0.z + v0.w * v0.w;
        ss += v1.x * v1.x + v1.y * v1.y + v1.z * v1.z + v1.w * v1.w;
        short8 av;
        av[0] = (short)f2bf(v0.x); av[1] = (short)f2bf(v0.y);
        av[2] = (short)f2bf(v0.z); av[3] = (short)f2bf(v0.w);
        av[4] = (short)f2bf(v1.x); av[5] = (short)f2bf(v1.y);
        av[6] = (short)f2bf(v1.z); av[7] = (short)f2bf(v1.w);
        a[rg][c] = av;
      }
      ss += __shfl_xor(ss, 16);
      ss += __shfl_xor(ss, 32);
      srow[rg] = ss;
    }
#pragma unroll
    for (int rg = 0; rg < 2; rg++)
#pragma unroll
      for (int r = 0; r < 4; r++)
        sr[rg][r] = __shfl(srow[rg], g * 4 + r);  // ||x||^2 of C-row 4g+r
  }
  __syncthreads();  // codebook staged; LDS read-only from here on

  // --- Sweep 32 column tiles of 16 codes; running weighted-argmin per lane.
  float vmin[2][4];
  int imin[2][4];
#pragma unroll
  for (int rg = 0; rg < 2; rg++)
#pragma unroll
    for (int r = 0; r < 4; r++) { vmin[rg][r] = 3.0e38f; imin[rg][r] = 0; }

  const short8* __restrict__ bbase = (const short8*)sm.frag + lane;
  for (int t = 0; t < 32; t++) {
    const int code = t * 16 + lr;         // B col = lane&15
    const float wt = sm.w[code];
    const float bb = sm.wse[code];
    const float m2w = -2.0f * wt;
    f32x4 acc0 = {0.f, 0.f, 0.f, 0.f};
    f32x4 acc1 = {0.f, 0.f, 0.f, 0.f};
#pragma unroll
    for (int c = 0; c < 4; c++) {
      short8 bf = bbase[(t * 4 + c) * 64];
      acc0 = __builtin_amdgcn_mfma_f32_16x16x32_bf16(a[0][c], bf, acc0, 0, 0, 0);
      acc1 = __builtin_amdgcn_mfma_f32_16x16x32_bf16(a[1][c], bf, acc1, 0, 0, 0);
    }
#pragma unroll
    for (int r = 0; r < 4; r++) {
      float v0 = fmaf(m2w, acc0[r], fmaf(wt, sr[0][r], bb));
      float v1 = fmaf(m2w, acc1[r], fmaf(wt, sr[1][r], bb));
      if (v0 < vmin[0][r]) { vmin[0][r] = v0; imin[0][r] = code; }
      if (v1 < vmin[1][r]) { vmin[1][r] = v1; imin[1][r] = code; }
    }
  }

  // --- Butterfly min-reduce across 16 lanes (tie -> smaller index).
  // Afterwards all 16 lanes of group g hold, in imin[rg][r], the winner of
  // C-row rg*16 + g*4 + r.
#pragma unroll
  for (int m = 1; m <= 8; m <<= 1) {
#pragma unroll
    for (int rg = 0; rg < 2; rg++)
#pragma unroll
      for (int r = 0; r < 4; r++) {
        float ov = __shfl_xor(vmin[rg][r], m);
        int oi = __shfl_xor(imin[rg][r], m);
        if (ov < vmin[rg][r] || (ov == vmin[rg][r] && oi < imin[rg][r])) {
          vmin[rg][r] = ov; imin[rg][r] = oi;
        }
      }
  }

  // --- Winner processing: indices out, loss partial (register-only).
  {
    float l0 = 0.f;
#pragma unroll
    for (int rg = 0; rg < 2; rg++)
#pragma unroll
      for (int r = 0; r < 4; r++) {
        int ci = imin[rg][r];
        l0 = fmaf(vmin[rg][r], sm.wrcp[ci], l0);
        if (lr == 0) out_idx[rowbase + rg * 16 + g * 4 + r] = (float)ci;
      }
    // Group values identical across 16 lanes; the two xors add one lane from
    // each other group -> exact sum over the wave's 32 rows.
    l0 += __shfl_xor(l0, 16);
    l0 += __shfl_xor(l0, 32);
    if (lane == 0) partials[blockIdx.x * NWAVES + wave] = l0;
  }

  // --- Wave-owned store: 32 rows x 128 f32; codes fetched from registers via
  // compile-time shfls (no LDS dependency, no barrier).
  {
    const uint4* __restrict__ esrc = (const uint4*)emb32;   // 32 uint4/row
    uint4* __restrict__ outu = (uint4*)out_q + rowbase * 32;
    const int col = lane & 31;
    const int hi = lane >> 5;               // 0: row 2it, 1: row 2it+1
#pragma unroll
    for (int it = 0; it < 16; it++) {
      const int row0 = 2 * it;              // compile-time
      const int rg = row0 >> 4;
      const int gn = (row0 >> 2) & 3;
      const int r0 = row0 & 3;              // even
      int c0 = __shfl(imin[rg][r0], gn * 16);
      int c1 = __shfl(imin[rg][r0 + 1], gn * 16);
      int code = hi ? c1 : c0;
      outu[it * 64 + lane] = esrc[code * 32 + col];
    }
  }
}

// ---------------- deterministic loss reduction ----------------
__global__ void vq_loss(const float* __restrict__ partials, float* __restrict__ out_loss) {
  __shared__ float red[16];
  const int t = threadIdx.x;
  float s = 0.f;
  for (int i = t; i < NBLOCKS * NWAVES; i += 1024) s += partials[i];
#pragma unroll
  for (int m = 1; m < 64; m <<= 1) s += __shfl_xor(s, m);
  if ((t & 63) == 0) red[t >> 6] = s;
  __syncthreads();
  if (t == 0) {
    float tot = 0.f;
    for (int i = 0; i < 16; i++) tot += red[i];
    // loss = (1 + 0.6) * mean((q - x)^2) over all QN elements
    out_loss[0] = tot * (1.6f / (float)QN);
  }
}

extern "C" void kernel_launch(void* const* d_in, const int* in_sizes, int n_in,
                              void* d_out, int out_size, void* d_ws, size_t ws_size,
                              hipStream_t stream) {
  const float* x = (const float*)d_in[0];
  const float* emb = (const float*)d_in[1];
  const float* scaling = (const float*)d_in[2];

  float* out_q = (float*)d_out;
  float* out_loss = out_q + QN;
  float* out_idx = out_q + QN + 1;

  unsigned short* emb_bf = (unsigned short*)d_ws;
  float* wv = (float*)((char*)d_ws + NCODES * DIM * 2);
  float* wse = wv + NCODES;
  float* wrcp = wse + NCODES;
  float* partials = wrcp + NCODES;

  vq_prep<<<NCODES, 64, 0, stream>>>(emb, scaling, emb_bf, wv, wse, wrcp);
  vq_main<<<NBLOCKS, 1024, 0, stream>>>(x, emb, emb_bf, wv, wse, wrcp,
                                        out_q, out_idx, partials);
  vq_loss<<<1, 1024, 0, stream>>>(partials, out_loss);
}